// Round 9
// baseline (45.944 us; speedup 1.0000x reference)
//
#include <hip/hip_runtime.h>
#include <hip/hip_bf16.h>

// Lovasz-Softmax loss, B=8, N=262144 (2^18), C=21, ignore_index=0.
// R9: R8 base (42.3us; K1 merge/scan verbatim). ONE change: K3 fused into
// K2 via deterministic u64 fixed-point atomic tail + last-block finish
// (saves one dispatch + launch gap). K1 block 0 zeroes the 16B header.
// History: R6/R7 K1 theories refuted (LDS-atomic contention, dwordx4);
// K1 ~35us = ~5.6 TB/s effective read-mix ceiling. R8: K2 merge latency
// was not a 4-5us cost. Launch-gap removal is the last cheap lever.

#define B_DIM 8
#define N_DIM 262144          // 2^18
#define NCLS 20               // classes 1..20
#define HB 256                // buckets
#define PX_PER_BLK 4096       // K1: 512 threads x 8 pixels
#define BLKS_PER_B 64         // 262144 / 4096
#define NBLK1 (B_DIM * BLKS_PER_B)   // 512
#define HSLOT (NCLS * HB)     // 5120 u32 per histogram (un-skewed)
#define RSTRIDE (HSLOT + 1)   // replica stride (+1 u32 bank skew)
#define FXSCALE 4398046511104.0  // 2^42

// ---------------------------------------------------------------------------
// Kernel 1: softmax + error bucketing -> per-block packed histograms.
// partial[blk][c-1][h] u32: lo16 = bg count, hi16 = fg count (<=4096 each).
// 2 LDS replicas split by half-wave. Block 0 zeroes the K2 header.
// ---------------------------------------------------------------------------
__global__ __launch_bounds__(512) void lovasz_hist1_kernel(
    const float* __restrict__ logits, const int* __restrict__ labels,
    unsigned* __restrict__ partials, unsigned* __restrict__ hdr) {
  __shared__ unsigned hist[2 * RSTRIDE];
  const int tid = threadIdx.x;

  if (blockIdx.x == 0 && tid < 4) hdr[tid] = 0;  // sumFx(u64), cnt, done

  for (int i = tid; i < 2 * RSTRIDE; i += 512) hist[i] = 0;
  __syncthreads();

  unsigned* myh = hist + ((tid >> 5) & 1) * RSTRIDE;
  const size_t base = (size_t)blockIdx.x * PX_PER_BLK;

  #pragma unroll
  for (int j = 0; j < 8; ++j) {
    const size_t p = base + tid + j * 512;
    const int lab = labels[p];
    const float* lp = logits + p * 21;
    float ex[21];
    float denom = 0.f;
    #pragma unroll
    for (int c = 0; c < 21; ++c) {
      ex[c] = __expf(lp[c]);
      denom += ex[c];
    }
    const float inv = 1.0f / denom;
    if (lab != 0) {
      #pragma unroll
      for (int c = 1; c <= NCLS; ++c) {
        const float pc = ex[c] * inv;
        const bool fg = (lab == c);
        const float e = fg ? (1.0f - pc) : pc;     // in (0,1)
        int h = (int)(e * (float)HB);
        h = h < (HB - 1) ? h : (HB - 1);
        atomicAdd(&myh[(c - 1) * HB + h], fg ? 0x10000u : 1u);
      }
    }
  }
  __syncthreads();

  unsigned* outp = partials + (size_t)blockIdx.x * HSLOT;
  for (int i = tid; i < HSLOT; i += 512)
    outp[i] = hist[i] + hist[i + RSTRIDE];
}

// ---------------------------------------------------------------------------
// Kernel 2: one block (512 thr) per (b, class) row.
// Merge: thread (g=tid>>6, l=tid&63) owns buckets [4l,4l+4), accumulates
// partials g, g+8, ..., g+56 via 8 independent coalesced uint4 loads.
// 8-group LDS reduce -> per-bucket (bg,fg) counts -> descending 256-bucket
// scan -> closed-form Lovasz term:
//   fg: term += n1*e/(K+m);  k += n1;
//   bg: term += (K-k)*e*n0/((K+m)*(K+m+n0));  m += n0;
// Tail (fused K3): include-mask from this row's own V; deterministic u64
// fixed-point atomic accumulation; last-arriving block writes the scalar.
// hdr: [0..1]=sumFx u64, [2]=cnt u32, [3]=done u32 (zeroed by K1 block 0).
// ---------------------------------------------------------------------------
__global__ __launch_bounds__(512) void lovasz_scan_kernel(
    const unsigned* __restrict__ partials, unsigned* __restrict__ hdr,
    float* __restrict__ out) {
  __shared__ unsigned slo[8][HB];
  __shared__ unsigned shi[8][HB];
  __shared__ unsigned ts1[256];
  __shared__ unsigned ts0[256];
  __shared__ float redf[256];
  __shared__ int redi[256];

  const int tid = threadIdx.x;
  const int g = tid >> 6;                      // partial-slice group 0..7
  const int l = tid & 63;                      // owns buckets 4l..4l+3
  const int row = blockIdx.x;                  // b*20 + ci
  const int b = row / NCLS;
  const int ci = row % NCLS;

  const unsigned* base = partials + (size_t)(b * BLKS_PER_B) * HSLOT + ci * HB;
  unsigned lo0 = 0, lo1 = 0, lo2 = 0, lo3 = 0;
  unsigned hi0 = 0, hi1 = 0, hi2 = 0, hi3 = 0;
  #pragma unroll
  for (int s = 0; s < 8; ++s) {
    const uint4 v = *(const uint4*)(base + (size_t)(g + s * 8) * HSLOT + l * 4);
    lo0 += v.x & 0xFFFFu; hi0 += v.x >> 16;
    lo1 += v.y & 0xFFFFu; hi1 += v.y >> 16;
    lo2 += v.z & 0xFFFFu; hi2 += v.z >> 16;
    lo3 += v.w & 0xFFFFu; hi3 += v.w >> 16;
  }
  slo[g][l * 4 + 0] = lo0; shi[g][l * 4 + 0] = hi0;
  slo[g][l * 4 + 1] = lo1; shi[g][l * 4 + 1] = hi1;
  slo[g][l * 4 + 2] = lo2; shi[g][l * 4 + 2] = hi2;
  slo[g][l * 4 + 3] = lo3; shi[g][l * 4 + 3] = hi3;
  __syncthreads();

  // Per-bucket totals: n0 = lo (bg), n1 = hi (fg) for bucket h = tid (<256).
  unsigned lo = 0, hi = 0;
  if (tid < 256) {
    #pragma unroll
    for (int gg = 0; gg < 8; ++gg) { lo += slo[gg][tid]; hi += shi[gg][tid]; }
    const int r = 255 - tid;                   // descending rank
    ts1[r] = hi; ts0[r] = lo;
  }
  __syncthreads();

  // Inclusive Hillis-Steele scan over descending rank (all threads barrier).
  for (int off = 1; off < 256; off <<= 1) {
    unsigned a1 = 0, a0 = 0;
    const int r = 255 - tid;
    const bool act = (tid < 256) && (r >= off);
    if (act) { a1 = ts1[r - off]; a0 = ts0[r - off]; }
    __syncthreads();
    if (act) { ts1[r] += a1; ts0[r] += a0; }
    __syncthreads();
  }
  const unsigned K = ts1[255];
  const unsigned V = K + ts0[255];             // valid pixels in batch b

  if (tid < 256) {
    float term = 0.f;
    if (K > 0) {
      const int r = 255 - tid;
      unsigned k = ts1[r] - hi;                // fg seen before my bucket
      const unsigned m = ts0[r] - lo;          // bg seen before my bucket
      const float e = ((float)tid + 0.5f) * (1.0f / (float)HB);
      if (hi) term += (float)hi * e / (float)(K + m);
      k += hi;
      if (lo) term += (float)(K - k) * e *
                      ((float)lo / ((float)(K + m) * (float)(K + m + lo)));
    }
    redf[tid] = term;
    redi[tid] = (lo | hi) ? tid : -1;
  }
  __syncthreads();

  for (int off = 128; off > 0; off >>= 1) {
    if (tid < off) {
      redf[tid] += redf[tid + off];
      redi[tid] = redi[tid] > redi[tid + off] ? redi[tid] : redi[tid + off];
    }
    __syncthreads();
  }

  if (tid == 0) {
    float t = redf[0];
    if (K == 0)   // degenerate: no fg -> grad=[1,0,...] -> max-error midpoint
      t = (redi[0] >= 0) ? ((float)redi[0] + 0.5f) * (1.0f / (float)HB) : 0.f;

    unsigned long long* sumFx = (unsigned long long*)hdr;
    if (V >= 2) {                              // include-mask for batch b
      atomicAdd(sumFx, (unsigned long long)((double)t * FXSCALE + 0.5));
      atomicAdd(&hdr[2], 1u);                  // included rows
    }
    __threadfence();
    if (atomicAdd(&hdr[3], 1u) == (unsigned)(B_DIM * NCLS - 1)) {
      const unsigned long long total = atomicAdd(sumFx, 0ULL);
      const unsigned count = atomicAdd(&hdr[2], 0u);
      out[0] = (float)((double)total / FXSCALE /
                       (double)(count > 0 ? count : 1));
    }
  }
}

extern "C" void kernel_launch(void* const* d_in, const int* in_sizes, int n_in,
                              void* d_out, int out_size, void* d_ws, size_t ws_size,
                              hipStream_t stream) {
  const float* logits = (const float*)d_in[0];
  const int* labels = (const int*)d_in[1];
  float* out = (float*)d_out;

  char* ws = (char*)d_ws;
  unsigned* hdr = (unsigned*)ws;                     // 4 u32 (K1-zeroed)
  unsigned* partials = (unsigned*)(ws + 1024);       // 512 * 5120 u32 = 10.5 MB

  lovasz_hist1_kernel<<<NBLK1, 512, 0, stream>>>(logits, labels, partials, hdr);
  lovasz_scan_kernel<<<B_DIM * NCLS, 512, 0, stream>>>(partials, hdr, out);
}

// Round 10
// 42.375 us; speedup vs baseline: 1.0842x; 1.0842x over previous
//
#include <hip/hip_runtime.h>
#include <hip/hip_bf16.h>

// Lovasz-Softmax loss, B=8, N=262144 (2^18), C=21, ignore_index=0.
// R10: revert to R8 verbatim (best: 42.28us). R9's fused atomic tail
// condemned (+3.6us: device-scope atomics + threadfence serialize block
// retirement; third loss for device atomics in this session).
// Structure: K1 histogram-build (streaming-limited ~35us = 195MB @ ~5.6TB/s
// effective; R6 LDS-atomic and R7 vectorization theories both refuted),
// K2 merge+scan+closed-form Lovasz (~3us), K3 tiny reduce.

#define B_DIM 8
#define N_DIM 262144          // 2^18
#define NCLS 20               // classes 1..20
#define HB 256                // buckets
#define PX_PER_BLK 4096       // K1: 512 threads x 8 pixels
#define BLKS_PER_B 64         // 262144 / 4096
#define NBLK1 (B_DIM * BLKS_PER_B)   // 512
#define HSLOT (NCLS * HB)     // 5120 u32 per histogram (un-skewed)
#define RSTRIDE (HSLOT + 1)   // replica stride (+1 u32 bank skew)

// ---------------------------------------------------------------------------
// Kernel 1: softmax + error bucketing -> per-block packed histograms.
// partial[blk][c-1][h] u32: lo16 = bg count, hi16 = fg count (<=4096 each).
// 2 LDS replicas split by half-wave.
// ---------------------------------------------------------------------------
__global__ __launch_bounds__(512) void lovasz_hist1_kernel(
    const float* __restrict__ logits, const int* __restrict__ labels,
    unsigned* __restrict__ partials) {
  __shared__ unsigned hist[2 * RSTRIDE];
  const int tid = threadIdx.x;

  for (int i = tid; i < 2 * RSTRIDE; i += 512) hist[i] = 0;
  __syncthreads();

  unsigned* myh = hist + ((tid >> 5) & 1) * RSTRIDE;
  const size_t base = (size_t)blockIdx.x * PX_PER_BLK;

  #pragma unroll
  for (int j = 0; j < 8; ++j) {
    const size_t p = base + tid + j * 512;
    const int lab = labels[p];
    const float* lp = logits + p * 21;
    float ex[21];
    float denom = 0.f;
    #pragma unroll
    for (int c = 0; c < 21; ++c) {
      ex[c] = __expf(lp[c]);
      denom += ex[c];
    }
    const float inv = 1.0f / denom;
    if (lab != 0) {
      #pragma unroll
      for (int c = 1; c <= NCLS; ++c) {
        const float pc = ex[c] * inv;
        const bool fg = (lab == c);
        const float e = fg ? (1.0f - pc) : pc;     // in (0,1)
        int h = (int)(e * (float)HB);
        h = h < (HB - 1) ? h : (HB - 1);
        atomicAdd(&myh[(c - 1) * HB + h], fg ? 0x10000u : 1u);
      }
    }
  }
  __syncthreads();

  unsigned* outp = partials + (size_t)blockIdx.x * HSLOT;
  for (int i = tid; i < HSLOT; i += 512)
    outp[i] = hist[i] + hist[i + RSTRIDE];
}

// ---------------------------------------------------------------------------
// Kernel 2: one block (512 thr) per (b, class) row.
// Merge: thread (g=tid>>6, l=tid&63) owns buckets [4l,4l+4) and accumulates
// partials g, g+8, ..., g+56 via 8 fully-unrolled uint4 loads (independent,
// coalesced 16B/lane). 8-group LDS reduce -> per-bucket (bg,fg) counts.
// Then descending 256-bucket scan + closed-form Lovasz term (guards: first
// 256 threads active, barriers executed by all).
//   fg: term += n1*e/(K+m);  k += n1;
//   bg: term += (K-k)*e*n0/((K+m)*(K+m+n0));  m += n0;
// Rows with ci==0 publish validCount[b].
// ---------------------------------------------------------------------------
__global__ __launch_bounds__(512) void lovasz_scan_kernel(
    const unsigned* __restrict__ partials, float* __restrict__ terms,
    unsigned* __restrict__ validCount) {
  __shared__ unsigned slo[8][HB];
  __shared__ unsigned shi[8][HB];
  __shared__ unsigned ts1[256];
  __shared__ unsigned ts0[256];
  __shared__ float redf[256];
  __shared__ int redi[256];

  const int tid = threadIdx.x;
  const int g = tid >> 6;                      // partial-slice group 0..7
  const int l = tid & 63;                      // owns buckets 4l..4l+3
  const int row = blockIdx.x;                  // b*20 + ci
  const int b = row / NCLS;
  const int ci = row % NCLS;

  const unsigned* base = partials + (size_t)(b * BLKS_PER_B) * HSLOT + ci * HB;
  unsigned lo0 = 0, lo1 = 0, lo2 = 0, lo3 = 0;
  unsigned hi0 = 0, hi1 = 0, hi2 = 0, hi3 = 0;
  #pragma unroll
  for (int s = 0; s < 8; ++s) {
    const uint4 v = *(const uint4*)(base + (size_t)(g + s * 8) * HSLOT + l * 4);
    lo0 += v.x & 0xFFFFu; hi0 += v.x >> 16;
    lo1 += v.y & 0xFFFFu; hi1 += v.y >> 16;
    lo2 += v.z & 0xFFFFu; hi2 += v.z >> 16;
    lo3 += v.w & 0xFFFFu; hi3 += v.w >> 16;
  }
  slo[g][l * 4 + 0] = lo0; shi[g][l * 4 + 0] = hi0;
  slo[g][l * 4 + 1] = lo1; shi[g][l * 4 + 1] = hi1;
  slo[g][l * 4 + 2] = lo2; shi[g][l * 4 + 2] = hi2;
  slo[g][l * 4 + 3] = lo3; shi[g][l * 4 + 3] = hi3;
  __syncthreads();

  // Per-bucket totals: n0 = lo (bg), n1 = hi (fg) for bucket h = tid (<256).
  unsigned lo = 0, hi = 0;
  if (tid < 256) {
    #pragma unroll
    for (int gg = 0; gg < 8; ++gg) { lo += slo[gg][tid]; hi += shi[gg][tid]; }
    const int r = 255 - tid;                   // descending rank
    ts1[r] = hi; ts0[r] = lo;
  }
  __syncthreads();

  // Inclusive Hillis-Steele scan over descending rank (all threads barrier).
  for (int off = 1; off < 256; off <<= 1) {
    unsigned a1 = 0, a0 = 0;
    const int r = 255 - tid;
    const bool act = (tid < 256) && (r >= off);
    if (act) { a1 = ts1[r - off]; a0 = ts0[r - off]; }
    __syncthreads();
    if (act) { ts1[r] += a1; ts0[r] += a0; }
    __syncthreads();
  }
  const unsigned K = ts1[255];
  const unsigned V = K + ts0[255];
  if (tid == 0 && ci == 0) validCount[b] = V;

  if (tid < 256) {
    float term = 0.f;
    if (K > 0) {
      const int r = 255 - tid;
      unsigned k = ts1[r] - hi;                // fg seen before my bucket
      const unsigned m = ts0[r] - lo;          // bg seen before my bucket
      const float e = ((float)tid + 0.5f) * (1.0f / (float)HB);
      if (hi) term += (float)hi * e / (float)(K + m);
      k += hi;
      if (lo) term += (float)(K - k) * e *
                      ((float)lo / ((float)(K + m) * (float)(K + m + lo)));
    }
    redf[tid] = term;
    redi[tid] = (lo | hi) ? tid : -1;
  }
  __syncthreads();

  for (int off = 128; off > 0; off >>= 1) {
    if (tid < off) {
      redf[tid] += redf[tid + off];
      redi[tid] = redi[tid] > redi[tid + off] ? redi[tid] : redi[tid + off];
    }
    __syncthreads();
  }

  if (tid == 0) {
    float t = redf[0];
    if (K == 0)   // degenerate: no fg -> grad=[1,0,...] -> max-error midpoint
      t = (redi[0] >= 0) ? ((float)redi[0] + 0.5f) * (1.0f / (float)HB) : 0.f;
    terms[row] = t;
  }
}

// ---------------------------------------------------------------------------
// Kernel 3: include-mask + final fixed-order reduction -> scalar loss.
// ---------------------------------------------------------------------------
__global__ __launch_bounds__(256) void lovasz_final_kernel(
    const float* __restrict__ terms, const unsigned* __restrict__ validCount,
    float* __restrict__ out) {
  __shared__ float red[256];
  const int t = threadIdx.x;
  float v = 0.f;
  if (t < B_DIM * NCLS) {
    const int b = t / NCLS;
    if (validCount[b] >= 2) v = terms[t];
  }
  red[t] = v;
  __syncthreads();
  for (int off = 128; off > 0; off >>= 1) {
    if (t < off) red[t] += red[t + off];
    __syncthreads();
  }
  if (t == 0) {
    int cnt = 0;
    #pragma unroll
    for (int b = 0; b < B_DIM; ++b) cnt += (validCount[b] >= 2) ? 1 : 0;
    const int count = cnt * NCLS;
    out[0] = red[0] / (float)(count > 0 ? count : 1);
  }
}

extern "C" void kernel_launch(void* const* d_in, const int* in_sizes, int n_in,
                              void* d_out, int out_size, void* d_ws, size_t ws_size,
                              hipStream_t stream) {
  const float* logits = (const float*)d_in[0];
  const int* labels = (const int*)d_in[1];
  float* out = (float*)d_out;

  char* ws = (char*)d_ws;
  unsigned* validCount = (unsigned*)ws;              // 8 * u32 (written by K2)
  float* terms = (float*)(ws + 64);                  // 160 * f32
  unsigned* partials = (unsigned*)(ws + 1024);       // 512 * 5120 u32 = 10.5 MB

  lovasz_hist1_kernel<<<NBLK1, 512, 0, stream>>>(logits, labels, partials);
  lovasz_scan_kernel<<<B_DIM * NCLS, 512, 0, stream>>>(partials, terms, validCount);
  lovasz_final_kernel<<<1, 256, 0, stream>>>(terms, validCount, out);
}